// Round 7
// baseline (419.875 us; speedup 1.0000x reference)
//
#include <hip/hip_runtime.h>
#include <hip/hip_bf16.h>

// Problem constants (fixed by setup_inputs)
#define BQ      2
#define QLEN    16384            // 128*128
#define CDIM    256
#define HEADS   8
#define LEV     3
#define PTS     4
#define DHEAD   32
#define NVTOT   13125            // 100*100 + 50*50 + 25*25
#define FDIM    1024
#define NTOK    (BQ*QLEN)        // 32768
#define MROWS_V (BQ*NVTOT)       // 26250
#define NPROJ   288              // 192 offsets + 96 attn logits, fused

typedef __attribute__((ext_vector_type(8))) short short8;     // 8 bf16 = 4 VGPRs
typedef __attribute__((ext_vector_type(4))) float floatx4;    // MFMA acc

typedef const __attribute__((address_space(1))) unsigned int gu32;
typedef __attribute__((address_space(3))) unsigned int lu32;

struct bf16x4 { __hip_bfloat16 v[4]; };

__device__ __forceinline__ int imin(int a, int b){ return a<b?a:b; }
__device__ __forceinline__ int imax(int a, int b){ return a>b?a:b; }

// saturation-safe fast gelu (tanh form); error ~3e-4 < bf16 rounding
__device__ __forceinline__ float gelu_f(float x)
{
    float u = 0.7978845608028654f * (x + 0.044715f * x * x * x);
    float e = __expf(2.0f * u);
    float th = 1.0f - 2.0f / (e + 1.0f);
    return 0.5f * x * (1.0f + th);
}

// ---------------------------------------------------------------- LayerNorm (+optional pos add), bf16 out
__global__ __launch_bounds__(256)
void ln_bf16_k(const float* __restrict__ x, const float* __restrict__ pos,
               const float* __restrict__ g, const float* __restrict__ b,
               __hip_bfloat16* __restrict__ out)
{
    int tok  = blockIdx.x * 4 + (threadIdx.x >> 6);
    int lane = threadIdx.x & 63;
    float4 v = ((const float4*)(x + (size_t)tok * CDIM))[lane];
    float s = v.x + v.y + v.z + v.w;
    #pragma unroll
    for (int o = 32; o > 0; o >>= 1) s += __shfl_down(s, o);
    s = __shfl(s, 0);
    float mean = s * (1.0f / 256.0f);
    float4 c; c.x = v.x - mean; c.y = v.y - mean; c.z = v.z - mean; c.w = v.w - mean;
    float q2 = c.x*c.x + c.y*c.y + c.z*c.z + c.w*c.w;
    #pragma unroll
    for (int o = 32; o > 0; o >>= 1) q2 += __shfl_down(q2, o);
    q2 = __shfl(q2, 0);
    float rstd = rsqrtf(q2 * (1.0f / 256.0f) + 1e-5f);
    float4 gg = ((const float4*)g)[lane];
    float4 bb = ((const float4*)b)[lane];
    float4 o4;
    o4.x = c.x * rstd * gg.x + bb.x;
    o4.y = c.y * rstd * gg.y + bb.y;
    o4.z = c.z * rstd * gg.z + bb.z;
    o4.w = c.w * rstd * gg.w + bb.w;
    if (pos) {
        float4 p = ((const float4*)(pos + (size_t)tok * CDIM))[lane];
        o4.x += p.x; o4.y += p.y; o4.z += p.z; o4.w += p.w;
    }
    bf16x4 r;
    r.v[0] = __float2bfloat16(o4.x); r.v[1] = __float2bfloat16(o4.y);
    r.v[2] = __float2bfloat16(o4.z); r.v[3] = __float2bfloat16(o4.w);
    ((bf16x4*)(out + (size_t)tok * CDIM))[lane] = r;
}

// ---------------------------------------------------------------- fp32 -> bf16 convert
__global__ __launch_bounds__(256)
void cvt_k(const float* __restrict__ in, __hip_bfloat16* __restrict__ out, int n4)
{
    int i = blockIdx.x * 256 + threadIdx.x;
    if (i >= n4) return;
    float4 v = ((const float4*)in)[i];
    bf16x4 r;
    r.v[0] = __float2bfloat16(v.x); r.v[1] = __float2bfloat16(v.y);
    r.v[2] = __float2bfloat16(v.z); r.v[3] = __float2bfloat16(v.w);
    ((bf16x4*)out)[i] = r;
}

// ---------------------------------------------------------------- fused weight transpose+convert (+combined proj weight & bias)
__global__ __launch_bounds__(256)
void wt_all_k(const float* __restrict__ Wv,  const float* __restrict__ Woff,
              const float* __restrict__ Wat, const float* __restrict__ Wout,
              const float* __restrict__ W1,  const float* __restrict__ W2,
              const float* __restrict__ boff, const float* __restrict__ bat,
              __hip_bfloat16* __restrict__ o_v,  __hip_bfloat16* __restrict__ o_c,
              __hip_bfloat16* __restrict__ o_out,
              __hip_bfloat16* __restrict__ o_1,  __hip_bfloat16* __restrict__ o_2,
              float* __restrict__ o_bc)
{
    int gid = blockIdx.x * 256 + threadIdx.x;
    if (gid < 65536) {                      // Wv  [256][256] -> [256][256]
        int idx = gid, n = idx >> 8, k = idx & 255;
        o_v[idx] = __float2bfloat16(Wv[(size_t)k * 256 + n]);
    } else if (gid < 163840) {              // combined proj -> [384][256]
        int idx = gid - 65536, n = idx >> 8, k = idx & 255;
        float v = 0.0f;
        if (n < 192)       v = Woff[(size_t)k * 192 + n];
        else if (n < 288)  v = Wat[(size_t)k * 96 + (n - 192)];
        o_c[idx] = __float2bfloat16(v);
    } else if (gid < 229376) {              // Wout [256][256]
        int idx = gid - 163840, n = idx >> 8, k = idx & 255;
        o_out[idx] = __float2bfloat16(Wout[(size_t)k * 256 + n]);
    } else if (gid < 491520) {              // W1 [256][1024] -> [1024][256]
        int idx = gid - 229376, n = idx >> 8, k = idx & 255;
        o_1[idx] = __float2bfloat16(W1[(size_t)k * 1024 + n]);
    } else if (gid < 753664) {              // W2 [1024][256] -> [256][1024]
        int idx = gid - 491520, n = idx >> 10, k = idx & 1023;
        o_2[idx] = __float2bfloat16(W2[(size_t)k * 256 + n]);
    } else if (gid < 753952) {              // combined bias [288]
        int idx = gid - 753664;
        o_bc[idx] = (idx < 192) ? boff[idx] : bat[idx - 192];
    }
}

// ---------------------------------------------------------------- bf16 MFMA GEMM (transposed-acc + LDS-staged epilogue)
// Weights = MFMA-A, tokens = MFMA-B -> lane's 4 acc regs = 4 consecutive channels
// of one token (vector bias/gelu). Epilogue stages each 64-token half through the
// (now free) 32 KB tile LDS so global stores are row-contiguous and coalesced.
// BK=64, XOR-swizzled LDS throughout; grid=(tokTiles, chanTiles) for XCD-local reuse.
enum { EP_PLAIN = 0, EP_VSCAT_BF16 = 1, EP_RES = 2, EP_GELU_BF16 = 3 };

__global__ __launch_bounds__(256)
void mm_k(const __hip_bfloat16* __restrict__ A, const __hip_bfloat16* __restrict__ Bt,
          const float* __restrict__ bias, const float* __restrict__ res,
          void* __restrict__ Cout, int M, int N, int K, int mode)
{
    __shared__ float4 smem4[2048];                    // 32 KB: tiles, then staging
    __hip_bfloat16* Ws = (__hip_bfloat16*)smem4;          // 16 KB weight tile
    __hip_bfloat16* Ts = (__hip_bfloat16*)smem4 + 128*64; // 16 KB token tile
    int t = threadIdx.x;
    int lane = t & 63;
    int wave = t >> 6;
    int wm = wave >> 1, wn = wave & 1;
    int lm = lane & 15, lk = lane >> 4;
    int m0 = blockIdx.x * 128;     // token base
    int n0 = blockIdx.y * 128;     // channel base

    floatx4 acc[4][4];             // [i: channel subtile][j: token subtile]
    #pragma unroll
    for (int i = 0; i < 4; i++)
        #pragma unroll
        for (int j = 0; j < 4; j++) acc[i][j] = (floatx4)0.0f;

    for (int kt = 0; kt < K; kt += 64) {
        #pragma unroll
        for (int i = 0; i < 4; i++) {
            int cc  = i * 256 + t;          // LDS chunk 0..1023 (16 B each)
            int row = cc >> 3;              // 0..127
            int c   = cc & 7;
            int kc  = c ^ (row & 7);        // XOR swizzle
            int ra  = m0 + row; if (ra >= M) ra = M - 1;   // token row clamp
            const __hip_bfloat16* gw = Bt + (size_t)(n0 + row) * K + kt + kc * 8;  // weights (padded N)
            const __hip_bfloat16* gt = A  + (size_t)ra * K + kt + kc * 8;          // tokens
            __builtin_amdgcn_global_load_lds((gu32*)gw, (lu32*)(Ws + cc * 8), 16, 0, 0);
            __builtin_amdgcn_global_load_lds((gu32*)gt, (lu32*)(Ts + cc * 8), 16, 0, 0);
        }
        __syncthreads();
        #pragma unroll
        for (int ks = 0; ks < 2; ks++) {
            short8 wf[4], tf[4];
            #pragma unroll
            for (int i = 0; i < 4; i++) {
                int rw = wn * 64 + i * 16 + lm;            // channel row
                int cw = (ks * 4 + lk) ^ (rw & 7);
                wf[i] = *(const short8*)(Ws + (rw * 8 + cw) * 8);
                int rt = wm * 64 + i * 16 + lm;            // token row
                int ct = (ks * 4 + lk) ^ (rt & 7);
                tf[i] = *(const short8*)(Ts + (rt * 8 + ct) * 8);
            }
            #pragma unroll
            for (int i = 0; i < 4; i++)
                #pragma unroll
                for (int j = 0; j < 4; j++)
                    acc[i][j] = __builtin_amdgcn_mfma_f32_16x16x32_bf16(wf[i], tf[j], acc[i][j], 0, 0, 0);
        }
        __syncthreads();
    }

    // ---- LDS-staged epilogue: two 64-token halves through 32 KB staging ----
    // staging chunk index = tl*32 + (ccol ^ (tl&7));  tl=token-local 0..63, ccol=chan>>2
    #pragma unroll
    for (int hh = 0; hh < 2; hh++) {
        if (hh) __syncthreads();           // protect staging reuse between halves
        if (wm == hh) {
            #pragma unroll
            for (int i = 0; i < 4; i++) {
                int chan = n0 + wn * 64 + i * 16 + lk * 4;
                float4 b4 = make_float4(0.f, 0.f, 0.f, 0.f);
                if (chan < N) b4 = *(const float4*)(bias + chan);
                int ccol = wn * 16 + i * 4 + lk;
                #pragma unroll
                for (int j = 0; j < 4; j++) {
                    int tl = j * 16 + lm;
                    float4 v;
                    v.x = acc[i][j][0] + b4.x;
                    v.y = acc[i][j][1] + b4.y;
                    v.z = acc[i][j][2] + b4.z;
                    v.w = acc[i][j][3] + b4.w;
                    smem4[tl * 32 + (ccol ^ (tl & 7))] = v;
                }
            }
        }
        __syncthreads();
        // read side: thread = (token tl = t>>2, 32-chan segment seg = t&3)
        int tl  = t >> 2;
        int seg = t & 3;
        int tok = m0 + hh * 64 + tl;
        int chan0 = n0 + seg * 32;
        if (tok < M && chan0 < N) {
            float4 c[8];
            #pragma unroll
            for (int u = 0; u < 8; u++)
                c[u] = smem4[tl * 32 + ((seg * 8 + u) ^ (tl & 7))];
            if (mode == EP_PLAIN) {
                float* p = (float*)Cout + (size_t)tok * N + chan0;
                #pragma unroll
                for (int u = 0; u < 8; u++) *(float4*)(p + u * 4) = c[u];
            } else if (mode == EP_RES) {
                const float* rp = res + (size_t)tok * N + chan0;
                float* p = (float*)Cout + (size_t)tok * N + chan0;
                #pragma unroll
                for (int u = 0; u < 8; u++) {
                    float4 rr = *(const float4*)(rp + u * 4);
                    float4 v = c[u];
                    v.x += rr.x; v.y += rr.y; v.z += rr.z; v.w += rr.w;
                    *(float4*)(p + u * 4) = v;
                }
            } else {
                __hip_bfloat16* p;
                if (mode == EP_VSCAT_BF16) {
                    int bb  = tok / NVTOT;
                    int pix = tok - bb * NVTOT;
                    int hd  = chan0 >> 5;     // 32 chans = exactly one head row
                    p = (__hip_bfloat16*)Cout
                        + (((size_t)(bb * HEADS + hd)) * NVTOT + pix) * DHEAD;
                } else { // EP_GELU_BF16
                    p = (__hip_bfloat16*)Cout + (size_t)tok * N + chan0;
                }
                #pragma unroll
                for (int u = 0; u < 8; u++) {
                    float4 v = c[u];
                    if (mode == EP_GELU_BF16) {
                        v.x = gelu_f(v.x); v.y = gelu_f(v.y);
                        v.z = gelu_f(v.z); v.w = gelu_f(v.w);
                    }
                    bf16x4 r;
                    r.v[0] = __float2bfloat16(v.x); r.v[1] = __float2bfloat16(v.y);
                    r.v[2] = __float2bfloat16(v.z); r.v[3] = __float2bfloat16(v.w);
                    *(bf16x4*)(p + u * 4) = r;
                }
            }
        }
    }
}

// ---------------------------------------------------------------- deformable sampling (inline softmax)
__global__ __launch_bounds__(256)
void sample_k(const __hip_bfloat16* __restrict__ v, const float* __restrict__ cbuf,
              const float* __restrict__ ref, __hip_bfloat16* __restrict__ out)
{
    __shared__ int4   metaIdx[4 * 104];   // stride 13 slots -> conflict-free
    __shared__ float4 metaW[4 * 104];

    int wid  = threadIdx.x >> 6;
    int lane = threadIdx.x & 63;
    int t    = blockIdx.x * 4 + wid;
    int b    = t >> 14;
    float rx = ref[(size_t)t * 2 + 0];
    float ry = ref[(size_t)t * 2 + 1];
    const float* crow = cbuf + (size_t)t * NPROJ;

    #pragma unroll
    for (int rnd = 0; rnd < 2; rnd++) {
        int slot = rnd * 64 + lane;
        int h = slot >> 4, p = slot & 15;
        int pc = imin(p, 11);
        float2 oxy  = *(const float2*)(crow + h * 24 + pc * 2);
        float logit = crow[192 + h * 12 + pc];
        float mx = logit;
        #pragma unroll
        for (int o = 8; o > 0; o >>= 1) mx = fmaxf(mx, __shfl_xor(mx, o, 16));
        float e = (p < 12) ? __expf(logit - mx) : 0.0f;
        float ssum = e;
        #pragma unroll
        for (int o = 8; o > 0; o >>= 1) ssum += __shfl_xor(ssum, o, 16);
        float aw = e / ssum;

        if (p < 12) {
            int l = p >> 2;
            float fS = (l == 0) ? 100.0f : ((l == 1) ? 50.0f : 25.0f);
            int   Wl = (l == 0) ? 100 : ((l == 1) ? 50 : 25);
            int   st = (l == 0) ? 0 : ((l == 1) ? 10000 : 12500);
            float x = (rx + oxy.x / fS) * fS - 0.5f;
            float y = (ry + oxy.y / fS) * fS - 0.5f;
            float x0f = floorf(x), y0f = floorf(y);
            float fx = x - x0f, fy = y - y0f;
            int x0 = (int)x0f, y0 = (int)y0f;
            int x1 = x0 + 1,  y1 = y0 + 1;
            int cx0 = imin(imax(x0, 0), Wl - 1), cx1 = imin(imax(x1, 0), Wl - 1);
            int cy0 = imin(imax(y0, 0), Wl - 1), cy1 = imin(imax(y1, 0), Wl - 1);
            float vx0 = (x0 >= 0 && x0 < Wl) ? 1.0f : 0.0f;
            float vx1 = (x1 >= 0 && x1 < Wl) ? 1.0f : 0.0f;
            float vy0 = (y0 >= 0 && y0 < Wl) ? 1.0f : 0.0f;
            float vy1 = (y1 >= 0 && y1 < Wl) ? 1.0f : 0.0f;
            int s = wid * 104 + h * 13 + p;
            metaIdx[s] = make_int4(st + cy0 * Wl + cx0, st + cy0 * Wl + cx1,
                                   st + cy1 * Wl + cx0, st + cy1 * Wl + cx1);
            metaW[s] = make_float4((1.0f - fx) * (1.0f - fy) * aw * vx0 * vy0,
                                   fx * (1.0f - fy) * aw * vx1 * vy0,
                                   (1.0f - fx) * fy * aw * vx0 * vy1,
                                   fx * fy * aw * vx1 * vy1);
        }
    }
    __syncthreads();

    int h  = lane >> 3;
    int c8 = lane & 7;
    const __hip_bfloat16* vbh = v + ((size_t)(b * HEADS + h)) * NVTOT * DHEAD + c8 * 4;
    float4 acc = {0.0f, 0.0f, 0.0f, 0.0f};
    #pragma unroll
    for (int p = 0; p < 12; p++) {
        int s = wid * 104 + h * 13 + p;
        int4   mi = metaIdx[s];
        float4 mw = metaW[s];
        ushort4 r0 = *(const ushort4*)(vbh + (size_t)mi.x * DHEAD);
        ushort4 r1 = *(const ushort4*)(vbh + (size_t)mi.y * DHEAD);
        ushort4 r2 = *(const ushort4*)(vbh + (size_t)mi.z * DHEAD);
        ushort4 r3 = *(const ushort4*)(vbh + (size_t)mi.w * DHEAD);
        acc.x = fmaf(mw.x, __uint_as_float((unsigned)r0.x << 16), acc.x);
        acc.y = fmaf(mw.x, __uint_as_float((unsigned)r0.y << 16), acc.y);
        acc.z = fmaf(mw.x, __uint_as_float((unsigned)r0.z << 16), acc.z);
        acc.w = fmaf(mw.x, __uint_as_float((unsigned)r0.w << 16), acc.w);
        acc.x = fmaf(mw.y, __uint_as_float((unsigned)r1.x << 16), acc.x);
        acc.y = fmaf(mw.y, __uint_as_float((unsigned)r1.y << 16), acc.y);
        acc.z = fmaf(mw.y, __uint_as_float((unsigned)r1.z << 16), acc.z);
        acc.w = fmaf(mw.y, __uint_as_float((unsigned)r1.w << 16), acc.w);
        acc.x = fmaf(mw.z, __uint_as_float((unsigned)r2.x << 16), acc.x);
        acc.y = fmaf(mw.z, __uint_as_float((unsigned)r2.y << 16), acc.y);
        acc.z = fmaf(mw.z, __uint_as_float((unsigned)r2.z << 16), acc.z);
        acc.w = fmaf(mw.z, __uint_as_float((unsigned)r2.w << 16), acc.w);
        acc.x = fmaf(mw.w, __uint_as_float((unsigned)r3.x << 16), acc.x);
        acc.y = fmaf(mw.w, __uint_as_float((unsigned)r3.y << 16), acc.y);
        acc.z = fmaf(mw.w, __uint_as_float((unsigned)r3.z << 16), acc.z);
        acc.w = fmaf(mw.w, __uint_as_float((unsigned)r3.w << 16), acc.w);
    }
    bf16x4 r;
    r.v[0] = __float2bfloat16(acc.x); r.v[1] = __float2bfloat16(acc.y);
    r.v[2] = __float2bfloat16(acc.z); r.v[3] = __float2bfloat16(acc.w);
    *(bf16x4*)(out + (size_t)t * CDIM + h * DHEAD + c8 * 4) = r;
}

// ---------------------------------------------------------------- launch
extern "C" void kernel_launch(void* const* d_in, const int* in_sizes, int n_in,
                              void* d_out, int out_size, void* d_ws, size_t ws_size,
                              hipStream_t stream)
{
    const float* query = (const float*)d_in[0];
    const float* value = (const float*)d_in[1];
    const float* qpos  = (const float*)d_in[2];
    const float* ref   = (const float*)d_in[3];
    const float* ln1g  = (const float*)d_in[6];
    const float* ln1b  = (const float*)d_in[7];
    const float* ln2g  = (const float*)d_in[8];
    const float* ln2b  = (const float*)d_in[9];
    const float* Wv    = (const float*)d_in[10];
    const float* bv    = (const float*)d_in[11];
    const float* Woff  = (const float*)d_in[12];
    const float* boff  = (const float*)d_in[13];
    const float* Wat   = (const float*)d_in[14];
    const float* bat   = (const float*)d_in[15];
    const float* Wout  = (const float*)d_in[16];
    const float* bout  = (const float*)d_in[17];
    const float* W1    = (const float*)d_in[18];
    const float* b1    = (const float*)d_in[19];
    const float* W2    = (const float*)d_in[20];
    const float* b2    = (const float*)d_in[21];
    float* out = (float*)d_out;
    char*  ws  = (char*)d_ws;

    const size_t MB = 1024 * 1024;
    __hip_bfloat16* Wvt   = (__hip_bfloat16*)(ws + 0);        // 256*256
    __hip_bfloat16* Wct   = (__hip_bfloat16*)(ws + 131072);   // 384*256 combined proj
    __hip_bfloat16* Woutt = (__hip_bfloat16*)(ws + 327680);   // 256*256
    __hip_bfloat16* W1t   = (__hip_bfloat16*)(ws + 458752);   // 1024*256
    __hip_bfloat16* W2t   = (__hip_bfloat16*)(ws + 983040);   // 256*1024
    float*          bcomb = (float*)(ws + 1507328);           // 288 floats
    __hip_bfloat16* qbf   = (__hip_bfloat16*)(ws + 2  * MB);  // 16.78 MB; reused as h
    __hip_bfloat16* aoutb = (__hip_bfloat16*)(ws + 19 * MB);  // 16.78 MB
    __hip_bfloat16* vbf   = (__hip_bfloat16*)(ws + 36 * MB);  // 13.44 MB (bf16 value input)
    __hip_bfloat16* vbuf  = (__hip_bfloat16*)(ws + 50 * MB);  // 13.44 MB scattered v (bf16)
    float*          cbuf  = (float*)(ws + 77 * MB);           // 37.75 MB fused proj (stride 288)
    __hip_bfloat16* gbf   = (__hip_bfloat16*)(ws + 50 * MB);  // 67.1 MB, aliases vbuf/cbuf (dead by FFN)
    __hip_bfloat16* hbf   = qbf;

    // 0. weights -> bf16 transposed (+ combined proj weight/bias), one launch
    wt_all_k<<<2946, 256, 0, stream>>>(Wv, Woff, Wat, Wout, W1, W2, boff, bat,
                                       Wvt, Wct, Woutt, W1t, W2t, bcomb);
    // 0b. value -> bf16
    cvt_k<<<(MROWS_V * CDIM / 4 + 255) / 256, 256, 0, stream>>>(value, vbf, MROWS_V * CDIM / 4);
    // 1. q = LN1(query) + query_pos  (bf16)
    ln_bf16_k<<<NTOK / 4, 256, 0, stream>>>(query, qpos, ln1g, ln1b, qbf);
    // 2. v = value @ W_value + b_value, scattered [b][h][pix][d] bf16
    mm_k<<<dim3((MROWS_V + 127) / 128, 2), 256, 0, stream>>>(
        vbf, Wvt, bv, nullptr, vbuf, MROWS_V, 256, 256, EP_VSCAT_BF16);
    // 3. fused proj: [offsets | attn logits] = q @ [W_off|W_attn] + [b_off|b_attn]
    mm_k<<<dim3(NTOK / 128, 3), 256, 0, stream>>>(
        qbf, Wct, bcomb, nullptr, cbuf, NTOK, NPROJ, 256, EP_PLAIN);
    // 4. sampling (inline softmax) -> aout bf16
    sample_k<<<NTOK / 4, 256, 0, stream>>>(vbuf, cbuf, ref, aoutb);
    // 5. x = query + aout @ W_out + b_out -> d_out fp32
    mm_k<<<dim3(NTOK / 128, 2), 256, 0, stream>>>(
        aoutb, Woutt, bout, query, out, NTOK, 256, 256, EP_RES);
    // 6. h = LN2(x)  bf16
    ln_bf16_k<<<NTOK / 4, 256, 0, stream>>>(out, nullptr, ln2g, ln2b, hbf);
    // 7. g = gelu(h @ W_ffn1 + b_ffn1)  bf16
    mm_k<<<dim3(NTOK / 128, 8), 256, 0, stream>>>(
        hbf, W1t, b1, nullptr, gbf, NTOK, FDIM, 256, EP_GELU_BF16);
    // 8. out = x + g @ W_ffn2 + b_ffn2  (in-place residual)
    mm_k<<<dim3(NTOK / 128, 2), 256, 0, stream>>>(
        gbf, W2t, b2, out, out, NTOK, 256, FDIM, EP_RES);
}

// Round 8
// 367.626 us; speedup vs baseline: 1.1421x; 1.1421x over previous
//
#include <hip/hip_runtime.h>
#include <hip/hip_bf16.h>

// Problem constants (fixed by setup_inputs)
#define BQ      2
#define QLEN    16384            // 128*128
#define CDIM    256
#define HEADS   8
#define LEV     3
#define PTS     4
#define DHEAD   32
#define NVTOT   13125            // 100*100 + 50*50 + 25*25
#define FDIM    1024
#define NTOK    (BQ*QLEN)        // 32768
#define MROWS_V (BQ*NVTOT)       // 26250
#define NPROJ   288              // 192 offsets + 96 attn logits, fused

typedef __attribute__((ext_vector_type(8))) short short8;     // 8 bf16 = 4 VGPRs
typedef __attribute__((ext_vector_type(4))) float floatx4;    // MFMA acc

typedef const __attribute__((address_space(1))) unsigned int gu32;
typedef __attribute__((address_space(3))) unsigned int lu32;

struct bf16x4 { __hip_bfloat16 v[4]; };

__device__ __forceinline__ int imin(int a, int b){ return a<b?a:b; }
__device__ __forceinline__ int imax(int a, int b){ return a>b?a:b; }

__device__ __forceinline__ float bf2f(unsigned short u){ return __uint_as_float((unsigned)u << 16); }
__device__ __forceinline__ unsigned short f2bf(float f)
{
    __hip_bfloat16 h = __float2bfloat16(f);
    return *(unsigned short*)&h;
}
// pack float4 -> 4 bf16 in a u64
__device__ __forceinline__ unsigned long long pack4(float4 v)
{
    unsigned long long r = (unsigned long long)f2bf(v.x)
                         | ((unsigned long long)f2bf(v.y) << 16)
                         | ((unsigned long long)f2bf(v.z) << 32)
                         | ((unsigned long long)f2bf(v.w) << 48);
    return r;
}
__device__ __forceinline__ float4 unpack4(unsigned long long c)
{
    float4 v;
    v.x = bf2f((unsigned short)(c));
    v.y = bf2f((unsigned short)(c >> 16));
    v.z = bf2f((unsigned short)(c >> 32));
    v.w = bf2f((unsigned short)(c >> 48));
    return v;
}

// saturation-safe fast gelu (tanh form); error ~3e-4 < bf16 rounding
__device__ __forceinline__ float gelu_f(float x)
{
    float u = 0.7978845608028654f * (x + 0.044715f * x * x * x);
    float e = __expf(2.0f * u);
    float th = 1.0f - 2.0f / (e + 1.0f);
    return 0.5f * x * (1.0f + th);
}

// ---------------------------------------------------------------- LayerNorm (+optional pos add), bf16 out
__global__ __launch_bounds__(256)
void ln_bf16_k(const float* __restrict__ x, const float* __restrict__ pos,
               const float* __restrict__ g, const float* __restrict__ b,
               __hip_bfloat16* __restrict__ out)
{
    int tok  = blockIdx.x * 4 + (threadIdx.x >> 6);
    int lane = threadIdx.x & 63;
    float4 v = ((const float4*)(x + (size_t)tok * CDIM))[lane];
    float s = v.x + v.y + v.z + v.w;
    #pragma unroll
    for (int o = 32; o > 0; o >>= 1) s += __shfl_down(s, o);
    s = __shfl(s, 0);
    float mean = s * (1.0f / 256.0f);
    float4 c; c.x = v.x - mean; c.y = v.y - mean; c.z = v.z - mean; c.w = v.w - mean;
    float q2 = c.x*c.x + c.y*c.y + c.z*c.z + c.w*c.w;
    #pragma unroll
    for (int o = 32; o > 0; o >>= 1) q2 += __shfl_down(q2, o);
    q2 = __shfl(q2, 0);
    float rstd = rsqrtf(q2 * (1.0f / 256.0f) + 1e-5f);
    float4 gg = ((const float4*)g)[lane];
    float4 bb = ((const float4*)b)[lane];
    float4 o4;
    o4.x = c.x * rstd * gg.x + bb.x;
    o4.y = c.y * rstd * gg.y + bb.y;
    o4.z = c.z * rstd * gg.z + bb.z;
    o4.w = c.w * rstd * gg.w + bb.w;
    if (pos) {
        float4 p = ((const float4*)(pos + (size_t)tok * CDIM))[lane];
        o4.x += p.x; o4.y += p.y; o4.z += p.z; o4.w += p.w;
    }
    *(unsigned long long*)(out + (size_t)tok * CDIM + lane * 4) = pack4(o4);
}

// ---------------------------------------------------------------- fp32 -> bf16 convert
__global__ __launch_bounds__(256)
void cvt_k(const float* __restrict__ in, __hip_bfloat16* __restrict__ out, int n4)
{
    int i = blockIdx.x * 256 + threadIdx.x;
    if (i >= n4) return;
    float4 v = ((const float4*)in)[i];
    *(unsigned long long*)(out + (size_t)i * 4) = pack4(v);
}

// ---------------------------------------------------------------- fused weight transpose+convert (+combined proj weight & bias)
__global__ __launch_bounds__(256)
void wt_all_k(const float* __restrict__ Wv,  const float* __restrict__ Woff,
              const float* __restrict__ Wat, const float* __restrict__ Wout,
              const float* __restrict__ W1,  const float* __restrict__ W2,
              const float* __restrict__ boff, const float* __restrict__ bat,
              __hip_bfloat16* __restrict__ o_v,  __hip_bfloat16* __restrict__ o_c,
              __hip_bfloat16* __restrict__ o_out,
              __hip_bfloat16* __restrict__ o_1,  __hip_bfloat16* __restrict__ o_2,
              float* __restrict__ o_bc)
{
    int gid = blockIdx.x * 256 + threadIdx.x;
    if (gid < 65536) {                      // Wv  [256][256] -> [256][256]
        int idx = gid, n = idx >> 8, k = idx & 255;
        o_v[idx] = __float2bfloat16(Wv[(size_t)k * 256 + n]);
    } else if (gid < 163840) {              // combined proj -> [384][256]
        int idx = gid - 65536, n = idx >> 8, k = idx & 255;
        float v = 0.0f;
        if (n < 192)       v = Woff[(size_t)k * 192 + n];
        else if (n < 288)  v = Wat[(size_t)k * 96 + (n - 192)];
        o_c[idx] = __float2bfloat16(v);
    } else if (gid < 229376) {              // Wout [256][256]
        int idx = gid - 163840, n = idx >> 8, k = idx & 255;
        o_out[idx] = __float2bfloat16(Wout[(size_t)k * 256 + n]);
    } else if (gid < 491520) {              // W1 [256][1024] -> [1024][256]
        int idx = gid - 229376, n = idx >> 8, k = idx & 255;
        o_1[idx] = __float2bfloat16(W1[(size_t)k * 1024 + n]);
    } else if (gid < 753664) {              // W2 [1024][256] -> [256][1024]
        int idx = gid - 491520, n = idx >> 10, k = idx & 1023;
        o_2[idx] = __float2bfloat16(W2[(size_t)k * 256 + n]);
    } else if (gid < 753952) {              // combined bias [288]
        int idx = gid - 753664;
        o_bc[idx] = (idx < 192) ? boff[idx] : bat[idx - 192];
    }
}

// ---------------------------------------------------------------- bf16 MFMA GEMM (transposed-acc + single-pass bf16-staged epilogue)
// Weights = MFMA-A, tokens = MFMA-B -> lane's 4 acc regs = 4 consecutive channels
// of one token. Epilogue: bias-add then pack bf16 and stage the FULL 128x128
// tile in the 32 KB tile LDS (all 4 waves concurrently, ONE extra barrier),
// then all 256 threads emit row-contiguous coalesced stores.
enum { EP_PLAIN_BF16 = 0, EP_VSCAT_BF16 = 1, EP_RES = 2, EP_GELU_BF16 = 3 };

__global__ __launch_bounds__(256)
void mm_k(const __hip_bfloat16* __restrict__ A, const __hip_bfloat16* __restrict__ Bt,
          const float* __restrict__ bias, const float* __restrict__ res,
          void* __restrict__ Cout, int M, int N, int K, int mode)
{
    __shared__ float4 smem4[2048];                    // 32 KB: tiles, then bf16 staging
    __hip_bfloat16* Ws = (__hip_bfloat16*)smem4;          // 16 KB weight tile
    __hip_bfloat16* Ts = (__hip_bfloat16*)smem4 + 128*64; // 16 KB token tile
    unsigned long long* st = (unsigned long long*)smem4;  // staging: 128 tok x 32 chunks x 8B
    int t = threadIdx.x;
    int lane = t & 63;
    int wave = t >> 6;
    int wm = wave >> 1, wn = wave & 1;
    int lm = lane & 15, lk = lane >> 4;
    int m0 = blockIdx.x * 128;     // token base
    int n0 = blockIdx.y * 128;     // channel base

    floatx4 acc[4][4];             // [i: channel subtile][j: token subtile]
    #pragma unroll
    for (int i = 0; i < 4; i++)
        #pragma unroll
        for (int j = 0; j < 4; j++) acc[i][j] = (floatx4)0.0f;

    for (int kt = 0; kt < K; kt += 64) {
        #pragma unroll
        for (int i = 0; i < 4; i++) {
            int cc  = i * 256 + t;          // LDS chunk 0..1023 (16 B each)
            int row = cc >> 3;              // 0..127
            int c   = cc & 7;
            int kc  = c ^ (row & 7);        // XOR swizzle
            int ra  = m0 + row; if (ra >= M) ra = M - 1;   // token row clamp
            const __hip_bfloat16* gw = Bt + (size_t)(n0 + row) * K + kt + kc * 8;  // weights (padded N)
            const __hip_bfloat16* gt = A  + (size_t)ra * K + kt + kc * 8;          // tokens
            __builtin_amdgcn_global_load_lds((gu32*)gw, (lu32*)(Ws + cc * 8), 16, 0, 0);
            __builtin_amdgcn_global_load_lds((gu32*)gt, (lu32*)(Ts + cc * 8), 16, 0, 0);
        }
        __syncthreads();
        #pragma unroll
        for (int ks = 0; ks < 2; ks++) {
            short8 wf[4], tf[4];
            #pragma unroll
            for (int i = 0; i < 4; i++) {
                int rw = wn * 64 + i * 16 + lm;            // channel row
                int cw = (ks * 4 + lk) ^ (rw & 7);
                wf[i] = *(const short8*)(Ws + (rw * 8 + cw) * 8);
                int rt = wm * 64 + i * 16 + lm;            // token row
                int ct = (ks * 4 + lk) ^ (rt & 7);
                tf[i] = *(const short8*)(Ts + (rt * 8 + ct) * 8);
            }
            #pragma unroll
            for (int i = 0; i < 4; i++)
                #pragma unroll
                for (int j = 0; j < 4; j++)
                    acc[i][j] = __builtin_amdgcn_mfma_f32_16x16x32_bf16(wf[i], tf[j], acc[i][j], 0, 0, 0);
        }
        __syncthreads();
    }

    // ---- write side: all waves stage bias-added bf16 frags (32 KB total) ----
    #pragma unroll
    for (int i = 0; i < 4; i++) {
        int chan = n0 + wn * 64 + i * 16 + lk * 4;
        float4 b4 = make_float4(0.f, 0.f, 0.f, 0.f);
        if (chan < N) b4 = *(const float4*)(bias + chan);
        int c4 = wn * 16 + i * 4 + lk;          // chan chunk 0..31
        #pragma unroll
        for (int j = 0; j < 4; j++) {
            int tl = wm * 64 + j * 16 + lm;     // token-local 0..127
            float4 v;
            v.x = acc[i][j][0] + b4.x;
            v.y = acc[i][j][1] + b4.y;
            v.z = acc[i][j][2] + b4.z;
            v.w = acc[i][j][3] + b4.w;
            st[tl * 32 + (c4 ^ (tl & 31))] = pack4(v);
        }
    }
    __syncthreads();

    // ---- read side: 16 iters, each 32-lane group covers one token row contiguously ----
    int rel  = (t & 31) * 4;                    // chan offset within tile
    int c4r  = t & 31;
    #pragma unroll
    for (int it = 0; it < 16; it++) {
        int tl   = it * 8 + (t >> 5);
        int tok  = m0 + tl;
        int chan = n0 + rel;
        if (tok >= M || chan >= N) continue;
        unsigned long long chunk = st[tl * 32 + (c4r ^ (tl & 31))];
        if (mode == EP_PLAIN_BF16) {
            *(unsigned long long*)((__hip_bfloat16*)Cout + (size_t)tok * N + chan) = chunk;
        } else if (mode == EP_VSCAT_BF16) {
            int bb  = tok / NVTOT;
            int pix = tok - bb * NVTOT;
            int hd  = chan >> 5, dc = chan & 31;
            *(unsigned long long*)((__hip_bfloat16*)Cout
                + (((size_t)(bb * HEADS + hd)) * NVTOT + pix) * DHEAD + dc) = chunk;
        } else if (mode == EP_GELU_BF16) {
            float4 v = unpack4(chunk);
            v.x = gelu_f(v.x); v.y = gelu_f(v.y); v.z = gelu_f(v.z); v.w = gelu_f(v.w);
            *(unsigned long long*)((__hip_bfloat16*)Cout + (size_t)tok * N + chan) = pack4(v);
        } else { // EP_RES: fp32 out = staged + residual
            float4 v = unpack4(chunk);
            float4 rr = *(const float4*)(res + (size_t)tok * N + chan);
            v.x += rr.x; v.y += rr.y; v.z += rr.z; v.w += rr.w;
            *(float4*)((float*)Cout + (size_t)tok * N + chan) = v;
        }
    }
}

// ---------------------------------------------------------------- deformable sampling (inline softmax, bf16 cbuf)
__global__ __launch_bounds__(256)
void sample_k(const __hip_bfloat16* __restrict__ v, const __hip_bfloat16* __restrict__ cbuf,
              const float* __restrict__ ref, __hip_bfloat16* __restrict__ out)
{
    __shared__ int4   metaIdx[4 * 104];   // stride 13 slots -> conflict-free
    __shared__ float4 metaW[4 * 104];

    int wid  = threadIdx.x >> 6;
    int lane = threadIdx.x & 63;
    int t    = blockIdx.x * 4 + wid;
    int b    = t >> 14;
    float rx = ref[(size_t)t * 2 + 0];
    float ry = ref[(size_t)t * 2 + 1];
    const __hip_bfloat16* crow = cbuf + (size_t)t * NPROJ;

    #pragma unroll
    for (int rnd = 0; rnd < 2; rnd++) {
        int slot = rnd * 64 + lane;
        int h = slot >> 4, p = slot & 15;
        int pc = imin(p, 11);
        unsigned upk = *(const unsigned*)(crow + h * 24 + pc * 2);
        float ox = bf2f((unsigned short)upk);
        float oy = bf2f((unsigned short)(upk >> 16));
        float logit = bf2f(*(const unsigned short*)(crow + 192 + h * 12 + pc));
        float mx = logit;
        #pragma unroll
        for (int o = 8; o > 0; o >>= 1) mx = fmaxf(mx, __shfl_xor(mx, o, 16));
        float e = (p < 12) ? __expf(logit - mx) : 0.0f;
        float ssum = e;
        #pragma unroll
        for (int o = 8; o > 0; o >>= 1) ssum += __shfl_xor(ssum, o, 16);
        float aw = e / ssum;

        if (p < 12) {
            int l = p >> 2;
            float fS = (l == 0) ? 100.0f : ((l == 1) ? 50.0f : 25.0f);
            int   Wl = (l == 0) ? 100 : ((l == 1) ? 50 : 25);
            int   st = (l == 0) ? 0 : ((l == 1) ? 10000 : 12500);
            float x = (rx + ox / fS) * fS - 0.5f;
            float y = (ry + oy / fS) * fS - 0.5f;
            float x0f = floorf(x), y0f = floorf(y);
            float fx = x - x0f, fy = y - y0f;
            int x0 = (int)x0f, y0 = (int)y0f;
            int x1 = x0 + 1,  y1 = y0 + 1;
            int cx0 = imin(imax(x0, 0), Wl - 1), cx1 = imin(imax(x1, 0), Wl - 1);
            int cy0 = imin(imax(y0, 0), Wl - 1), cy1 = imin(imax(y1, 0), Wl - 1);
            float vx0 = (x0 >= 0 && x0 < Wl) ? 1.0f : 0.0f;
            float vx1 = (x1 >= 0 && x1 < Wl) ? 1.0f : 0.0f;
            float vy0 = (y0 >= 0 && y0 < Wl) ? 1.0f : 0.0f;
            float vy1 = (y1 >= 0 && y1 < Wl) ? 1.0f : 0.0f;
            int s = wid * 104 + h * 13 + p;
            metaIdx[s] = make_int4(st + cy0 * Wl + cx0, st + cy0 * Wl + cx1,
                                   st + cy1 * Wl + cx0, st + cy1 * Wl + cx1);
            metaW[s] = make_float4((1.0f - fx) * (1.0f - fy) * aw * vx0 * vy0,
                                   fx * (1.0f - fy) * aw * vx1 * vy0,
                                   (1.0f - fx) * fy * aw * vx0 * vy1,
                                   fx * fy * aw * vx1 * vy1);
        }
    }
    __syncthreads();

    int h  = lane >> 3;
    int c8 = lane & 7;
    const __hip_bfloat16* vbh = v + ((size_t)(b * HEADS + h)) * NVTOT * DHEAD + c8 * 4;
    float4 acc = {0.0f, 0.0f, 0.0f, 0.0f};
    #pragma unroll
    for (int p = 0; p < 12; p++) {
        int s = wid * 104 + h * 13 + p;
        int4   mi = metaIdx[s];
        float4 mw = metaW[s];
        ushort4 r0 = *(const ushort4*)(vbh + (size_t)mi.x * DHEAD);
        ushort4 r1 = *(const ushort4*)(vbh + (size_t)mi.y * DHEAD);
        ushort4 r2 = *(const ushort4*)(vbh + (size_t)mi.z * DHEAD);
        ushort4 r3 = *(const ushort4*)(vbh + (size_t)mi.w * DHEAD);
        acc.x = fmaf(mw.x, bf2f(r0.x), acc.x);
        acc.y = fmaf(mw.x, bf2f(r0.y), acc.y);
        acc.z = fmaf(mw.x, bf2f(r0.z), acc.z);
        acc.w = fmaf(mw.x, bf2f(r0.w), acc.w);
        acc.x = fmaf(mw.y, bf2f(r1.x), acc.x);
        acc.y = fmaf(mw.y, bf2f(r1.y), acc.y);
        acc.z = fmaf(mw.y, bf2f(r1.z), acc.z);
        acc.w = fmaf(mw.y, bf2f(r1.w), acc.w);
        acc.x = fmaf(mw.z, bf2f(r2.x), acc.x);
        acc.y = fmaf(mw.z, bf2f(r2.y), acc.y);
        acc.z = fmaf(mw.z, bf2f(r2.z), acc.z);
        acc.w = fmaf(mw.z, bf2f(r2.w), acc.w);
        acc.x = fmaf(mw.w, bf2f(r3.x), acc.x);
        acc.y = fmaf(mw.w, bf2f(r3.y), acc.y);
        acc.z = fmaf(mw.w, bf2f(r3.z), acc.z);
        acc.w = fmaf(mw.w, bf2f(r3.w), acc.w);
    }
    *(unsigned long long*)(out + (size_t)t * CDIM + h * DHEAD + c8 * 4) = pack4(acc);
}

// ---------------------------------------------------------------- launch
extern "C" void kernel_launch(void* const* d_in, const int* in_sizes, int n_in,
                              void* d_out, int out_size, void* d_ws, size_t ws_size,
                              hipStream_t stream)
{
    const float* query = (const float*)d_in[0];
    const float* value = (const float*)d_in[1];
    const float* qpos  = (const float*)d_in[2];
    const float* ref   = (const float*)d_in[3];
    const float* ln1g  = (const float*)d_in[6];
    const float* ln1b  = (const float*)d_in[7];
    const float* ln2g  = (const float*)d_in[8];
    const float* ln2b  = (const float*)d_in[9];
    const float* Wv    = (const float*)d_in[10];
    const float* bv    = (const float*)d_in[11];
    const float* Woff  = (const float*)d_in[12];
    const float* boff  = (const float*)d_in[13];
    const float* Wat   = (const float*)d_in[14];
    const float* bat   = (const float*)d_in[15];
    const float* Wout  = (const float*)d_in[16];
    const float* bout  = (const float*)d_in[17];
    const float* W1    = (const float*)d_in[18];
    const float* b1    = (const float*)d_in[19];
    const float* W2    = (const float*)d_in[20];
    const float* b2    = (const float*)d_in[21];
    float* out = (float*)d_out;
    char*  ws  = (char*)d_ws;

    const size_t MB = 1024 * 1024;
    __hip_bfloat16* Wvt   = (__hip_bfloat16*)(ws + 0);        // 256*256
    __hip_bfloat16* Wct   = (__hip_bfloat16*)(ws + 131072);   // 384*256 combined proj
    __hip_bfloat16* Woutt = (__hip_bfloat16*)(ws + 327680);   // 256*256
    __hip_bfloat16* W1t   = (__hip_bfloat16*)(ws + 458752);   // 1024*256
    __hip_bfloat16* W2t   = (__hip_bfloat16*)(ws + 983040);   // 256*1024
    float*          bcomb = (float*)(ws + 1507328);           // 288 floats
    __hip_bfloat16* qbf   = (__hip_bfloat16*)(ws + 2  * MB);  // 16.78 MB; reused as h
    __hip_bfloat16* aoutb = (__hip_bfloat16*)(ws + 19 * MB);  // 16.78 MB
    __hip_bfloat16* vbf   = (__hip_bfloat16*)(ws + 36 * MB);  // 13.44 MB (bf16 value input)
    __hip_bfloat16* vbuf  = (__hip_bfloat16*)(ws + 50 * MB);  // 13.44 MB scattered v (bf16)
    __hip_bfloat16* cbuf  = (__hip_bfloat16*)(ws + 77 * MB);  // 18.9 MB fused proj (bf16, stride 288)
    __hip_bfloat16* gbf   = (__hip_bfloat16*)(ws + 100 * MB); // 67.1 MB gelu acts
    __hip_bfloat16* hbf   = qbf;

    // 0. weights -> bf16 transposed (+ combined proj weight/bias), one launch
    wt_all_k<<<2946, 256, 0, stream>>>(Wv, Woff, Wat, Wout, W1, W2, boff, bat,
                                       Wvt, Wct, Woutt, W1t, W2t, bcomb);
    // 0b. value -> bf16
    cvt_k<<<(MROWS_V * CDIM / 4 + 255) / 256, 256, 0, stream>>>(value, vbf, MROWS_V * CDIM / 4);
    // 1. q = LN1(query) + query_pos  (bf16)
    ln_bf16_k<<<NTOK / 4, 256, 0, stream>>>(query, qpos, ln1g, ln1b, qbf);
    // 2. v = value @ W_value + b_value, scattered [b][h][pix][d] bf16
    mm_k<<<dim3((MROWS_V + 127) / 128, 2), 256, 0, stream>>>(
        vbf, Wvt, bv, nullptr, vbuf, MROWS_V, 256, 256, EP_VSCAT_BF16);
    // 3. fused proj: [offsets | attn logits] = q @ [W_off|W_attn] + bias  (bf16)
    mm_k<<<dim3(NTOK / 128, 3), 256, 0, stream>>>(
        qbf, Wct, bcomb, nullptr, cbuf, NTOK, NPROJ, 256, EP_PLAIN_BF16);
    // 4. sampling (inline softmax) -> aout bf16
    sample_k<<<NTOK / 4, 256, 0, stream>>>(vbuf, cbuf, ref, aoutb);
    // 5. x = query + aout @ W_out + b_out -> d_out fp32
    mm_k<<<dim3(NTOK / 128, 2), 256, 0, stream>>>(
        aoutb, Woutt, bout, query, out, NTOK, 256, 256, EP_RES);
    // 6. h = LN2(x)  bf16
    ln_bf16_k<<<NTOK / 4, 256, 0, stream>>>(out, nullptr, ln2g, ln2b, hbf);
    // 7. g = gelu(h @ W_ffn1 + b_ffn1)  bf16
    mm_k<<<dim3(NTOK / 128, 8), 256, 0, stream>>>(
        hbf, W1t, b1, nullptr, gbf, NTOK, FDIM, 256, EP_GELU_BF16);
    // 8. out = x + g @ W_ffn2 + b_ffn2  (in-place residual)
    mm_k<<<dim3(NTOK / 128, 2), 256, 0, stream>>>(
        gbf, W2t, b2, out, out, NTOK, 256, FDIM, EP_RES);
}

// Round 9
// 347.792 us; speedup vs baseline: 1.2073x; 1.0570x over previous
//
#include <hip/hip_runtime.h>
#include <hip/hip_bf16.h>

// Problem constants (fixed by setup_inputs)
#define BQ      2
#define QLEN    16384            // 128*128
#define CDIM    256
#define HEADS   8
#define LEV     3
#define PTS     4
#define DHEAD   32
#define NVTOT   13125            // 100*100 + 50*50 + 25*25
#define FDIM    1024
#define NTOK    (BQ*QLEN)        // 32768
#define MROWS_V (BQ*NVTOT)       // 26250
#define NPROJ   288              // 192 offsets + 96 attn logits, fused

typedef __attribute__((ext_vector_type(8))) short short8;     // 8 bf16 = 4 VGPRs
typedef __attribute__((ext_vector_type(4))) float floatx4;    // MFMA acc
typedef unsigned long long u64;

typedef const __attribute__((address_space(1))) unsigned int gu32;
typedef __attribute__((address_space(3))) unsigned int lu32;

__device__ __forceinline__ int imin(int a, int b){ return a<b?a:b; }
__device__ __forceinline__ int imax(int a, int b){ return a>b?a:b; }

__device__ __forceinline__ float bf2f(unsigned short u){ return __uint_as_float((unsigned)u << 16); }
__device__ __forceinline__ unsigned short f2bf(float f)
{
    __hip_bfloat16 h = __float2bfloat16(f);
    return *(unsigned short*)&h;
}
__device__ __forceinline__ u64 pack4(float4 v)
{
    return (u64)f2bf(v.x) | ((u64)f2bf(v.y) << 16)
         | ((u64)f2bf(v.z) << 32) | ((u64)f2bf(v.w) << 48);
}
__device__ __forceinline__ float4 unpack4(u64 c)
{
    float4 v;
    v.x = bf2f((unsigned short)(c));
    v.y = bf2f((unsigned short)(c >> 16));
    v.z = bf2f((unsigned short)(c >> 32));
    v.w = bf2f((unsigned short)(c >> 48));
    return v;
}

// tanh-gelu via exp + hardware rcp (no div sequence); err ~3e-4, saturation-safe
__device__ __forceinline__ float gelu_f(float x)
{
    float u2 = x * x;
    float a  = x * fmaf(0.0713548163f, u2, 1.5957691216f);  // 2u
    float e  = __expf(a);
    float r  = __builtin_amdgcn_rcpf(e + 1.0f);
    return fmaf(-x, r, x);   // x * e/(e+1)
}

// LayerNorm core: one wave per token (4 ch per lane), bf16 out
__device__ __forceinline__ void ln_core(float4 v, const float* __restrict__ pos, int tok,
                                        const float* __restrict__ g, const float* __restrict__ b,
                                        int lane, __hip_bfloat16* __restrict__ out)
{
    float s = v.x + v.y + v.z + v.w;
    #pragma unroll
    for (int o = 32; o > 0; o >>= 1) s += __shfl_down(s, o);
    s = __shfl(s, 0);
    float mean = s * (1.0f / 256.0f);
    float4 c; c.x = v.x - mean; c.y = v.y - mean; c.z = v.z - mean; c.w = v.w - mean;
    float q2 = c.x*c.x + c.y*c.y + c.z*c.z + c.w*c.w;
    #pragma unroll
    for (int o = 32; o > 0; o >>= 1) q2 += __shfl_down(q2, o);
    q2 = __shfl(q2, 0);
    float rstd = rsqrtf(q2 * (1.0f / 256.0f) + 1e-5f);
    float4 gg = ((const float4*)g)[lane];
    float4 bb = ((const float4*)b)[lane];
    float4 o4;
    o4.x = c.x * rstd * gg.x + bb.x;
    o4.y = c.y * rstd * gg.y + bb.y;
    o4.z = c.z * rstd * gg.z + bb.z;
    o4.w = c.w * rstd * gg.w + bb.w;
    if (pos) {
        float4 p = ((const float4*)(pos + (size_t)tok * CDIM))[lane];
        o4.x += p.x; o4.y += p.y; o4.z += p.z; o4.w += p.w;
    }
    *(u64*)(out + (size_t)tok * CDIM + lane * 4) = pack4(o4);
}

// ---------------------------------------------------------------- prep: weight transpose+cvt + value cvt + LN1, one launch
#define WT_BLOCKS  2946
#define CVT_BLOCKS 6563          // ceil(26250*256/4 / 256)
#define LN_BLOCKS  8192          // NTOK/4

__global__ __launch_bounds__(256)
void prep_k(const float* __restrict__ Wv,  const float* __restrict__ Woff,
            const float* __restrict__ Wat, const float* __restrict__ Wout,
            const float* __restrict__ W1,  const float* __restrict__ W2,
            const float* __restrict__ boff, const float* __restrict__ bat,
            const float* __restrict__ value, const float* __restrict__ query,
            const float* __restrict__ qpos,  const float* __restrict__ ln1g,
            const float* __restrict__ ln1b,
            __hip_bfloat16* __restrict__ o_v,  __hip_bfloat16* __restrict__ o_c,
            __hip_bfloat16* __restrict__ o_out,
            __hip_bfloat16* __restrict__ o_1,  __hip_bfloat16* __restrict__ o_2,
            float* __restrict__ o_bc,
            __hip_bfloat16* __restrict__ vbf,  __hip_bfloat16* __restrict__ qbf)
{
    int bx = blockIdx.x;
    if (bx < WT_BLOCKS) {
        int gid = bx * 256 + threadIdx.x;
        if (gid < 65536) {                      // Wv  -> [256][256]
            int idx = gid, n = idx >> 8, k = idx & 255;
            o_v[idx] = __float2bfloat16(Wv[(size_t)k * 256 + n]);
        } else if (gid < 163840) {              // combined proj -> [384][256]
            int idx = gid - 65536, n = idx >> 8, k = idx & 255;
            float v = 0.0f;
            if (n < 192)       v = Woff[(size_t)k * 192 + n];
            else if (n < 288)  v = Wat[(size_t)k * 96 + (n - 192)];
            o_c[idx] = __float2bfloat16(v);
        } else if (gid < 229376) {              // Wout -> [256][256]
            int idx = gid - 163840, n = idx >> 8, k = idx & 255;
            o_out[idx] = __float2bfloat16(Wout[(size_t)k * 256 + n]);
        } else if (gid < 491520) {              // W1 -> [1024][256]
            int idx = gid - 229376, n = idx >> 8, k = idx & 255;
            o_1[idx] = __float2bfloat16(W1[(size_t)k * 1024 + n]);
        } else if (gid < 753664) {              // W2 -> [256][1024]
            int idx = gid - 491520, n = idx >> 10, k = idx & 1023;
            o_2[idx] = __float2bfloat16(W2[(size_t)k * 256 + n]);
        } else if (gid < 753952) {              // combined bias [288]
            int idx = gid - 753664;
            o_bc[idx] = (idx < 192) ? boff[idx] : bat[idx - 192];
        }
    } else if (bx < WT_BLOCKS + CVT_BLOCKS) {
        int i = (bx - WT_BLOCKS) * 256 + threadIdx.x;
        if (i < MROWS_V * CDIM / 4) {
            float4 v = ((const float4*)value)[i];
            *(u64*)(vbf + (size_t)i * 4) = pack4(v);
        }
    } else {
        int tok  = (bx - WT_BLOCKS - CVT_BLOCKS) * 4 + (threadIdx.x >> 6);
        int lane = threadIdx.x & 63;
        float4 v = ((const float4*)(query + (size_t)tok * CDIM))[lane];
        ln_core(v, qpos, tok, ln1g, ln1b, lane, qbf);
    }
}

// ---------------------------------------------------------------- LN2: bf16 in, bf16 out
__global__ __launch_bounds__(256)
void ln2_k(const __hip_bfloat16* __restrict__ x, const float* __restrict__ g,
           const float* __restrict__ b, __hip_bfloat16* __restrict__ out)
{
    int tok  = blockIdx.x * 4 + (threadIdx.x >> 6);
    int lane = threadIdx.x & 63;
    float4 v = unpack4(((const u64*)(x + (size_t)tok * CDIM))[lane]);
    ln_core(v, nullptr, tok, g, b, lane, out);
}

// ---------------------------------------------------------------- bf16 MFMA GEMM (transposed-acc + single-pass bf16-staged epilogue)
// modes: 0 = plain bf16 out; 1 = gelu bf16 out; 2 = +fp32 res -> bf16 out; 3 = +bf16 res -> fp32 out
enum { EP_PLAIN_BF16 = 0, EP_GELU_BF16 = 1, EP_RES_F2BF = 2, EP_RES_BF2F = 3 };

__global__ __launch_bounds__(256)
void mm_k(const __hip_bfloat16* __restrict__ A, const __hip_bfloat16* __restrict__ Bt,
          const float* __restrict__ bias, const void* __restrict__ res,
          void* __restrict__ Cout, int M, int N, int K, int mode)
{
    __shared__ float4 smem4[2048];                    // 32 KB: tiles, then bf16 staging
    __hip_bfloat16* Ws = (__hip_bfloat16*)smem4;          // 16 KB weight tile
    __hip_bfloat16* Ts = (__hip_bfloat16*)smem4 + 128*64; // 16 KB token tile
    u64* st = (u64*)smem4;                                // staging: 128 tok x 32 chunks x 8B
    int t = threadIdx.x;
    int lane = t & 63;
    int wave = t >> 6;
    int wm = wave >> 1, wn = wave & 1;
    int lm = lane & 15, lk = lane >> 4;
    int m0 = blockIdx.x * 128;     // token base
    int n0 = blockIdx.y * 128;     // channel base

    floatx4 acc[4][4];             // [i: channel subtile][j: token subtile]
    #pragma unroll
    for (int i = 0; i < 4; i++)
        #pragma unroll
        for (int j = 0; j < 4; j++) acc[i][j] = (floatx4)0.0f;

    for (int kt = 0; kt < K; kt += 64) {
        #pragma unroll
        for (int i = 0; i < 4; i++) {
            int cc  = i * 256 + t;          // LDS chunk 0..1023 (16 B each)
            int row = cc >> 3;              // 0..127
            int c   = cc & 7;
            int kc  = c ^ (row & 7);        // XOR swizzle
            int ra  = m0 + row; if (ra >= M) ra = M - 1;   // token row clamp
            const __hip_bfloat16* gw = Bt + (size_t)(n0 + row) * K + kt + kc * 8;
            const __hip_bfloat16* gt = A  + (size_t)ra * K + kt + kc * 8;
            __builtin_amdgcn_global_load_lds((gu32*)gw, (lu32*)(Ws + cc * 8), 16, 0, 0);
            __builtin_amdgcn_global_load_lds((gu32*)gt, (lu32*)(Ts + cc * 8), 16, 0, 0);
        }
        __syncthreads();
        #pragma unroll
        for (int ks = 0; ks < 2; ks++) {
            short8 wf[4], tf[4];
            #pragma unroll
            for (int i = 0; i < 4; i++) {
                int rw = wn * 64 + i * 16 + lm;            // channel row
                int cw = (ks * 4 + lk) ^ (rw & 7);
                wf[i] = *(const short8*)(Ws + (rw * 8 + cw) * 8);
                int rt = wm * 64 + i * 16 + lm;            // token row
                int ct = (ks * 4 + lk) ^ (rt & 7);
                tf[i] = *(const short8*)(Ts + (rt * 8 + ct) * 8);
            }
            #pragma unroll
            for (int i = 0; i < 4; i++)
                #pragma unroll
                for (int j = 0; j < 4; j++)
                    acc[i][j] = __builtin_amdgcn_mfma_f32_16x16x32_bf16(wf[i], tf[j], acc[i][j], 0, 0, 0);
        }
        __syncthreads();
    }

    // ---- write side: all waves stage bias-added bf16 frags ----
    #pragma unroll
    for (int i = 0; i < 4; i++) {
        int chan = n0 + wn * 64 + i * 16 + lk * 4;
        float4 b4 = make_float4(0.f, 0.f, 0.f, 0.f);
        if (chan < N) b4 = *(const float4*)(bias + chan);
        int c4 = wn * 16 + i * 4 + lk;          // chan chunk 0..31
        #pragma unroll
        for (int j = 0; j < 4; j++) {
            int tl = wm * 64 + j * 16 + lm;     // token-local 0..127
            float4 v;
            v.x = acc[i][j][0] + b4.x;
            v.y = acc[i][j][1] + b4.y;
            v.z = acc[i][j][2] + b4.z;
            v.w = acc[i][j][3] + b4.w;
            st[tl * 32 + (c4 ^ (tl & 31))] = pack4(v);
        }
    }
    __syncthreads();

    // ---- read side: coalesced row-contiguous stores ----
    int rel = (t & 31) * 4;
    int c4r = t & 31;
    #pragma unroll
    for (int it = 0; it < 16; it++) {
        int tl   = it * 8 + (t >> 5);
        int tok  = m0 + tl;
        int chan = n0 + rel;
        if (tok >= M || chan >= N) continue;
        u64 chunk = st[tl * 32 + (c4r ^ (tl & 31))];
        if (mode == EP_PLAIN_BF16) {
            *(u64*)((__hip_bfloat16*)Cout + (size_t)tok * N + chan) = chunk;
        } else if (mode == EP_GELU_BF16) {
            float4 v = unpack4(chunk);
            v.x = gelu_f(v.x); v.y = gelu_f(v.y); v.z = gelu_f(v.z); v.w = gelu_f(v.w);
            *(u64*)((__hip_bfloat16*)Cout + (size_t)tok * N + chan) = pack4(v);
        } else if (mode == EP_RES_F2BF) {
            float4 v = unpack4(chunk);
            float4 rr = *(const float4*)((const float*)res + (size_t)tok * N + chan);
            v.x += rr.x; v.y += rr.y; v.z += rr.z; v.w += rr.w;
            *(u64*)((__hip_bfloat16*)Cout + (size_t)tok * N + chan) = pack4(v);
        } else { // EP_RES_BF2F
            float4 v = unpack4(chunk);
            float4 rr = unpack4(*(const u64*)((const __hip_bfloat16*)res + (size_t)tok * N + chan));
            v.x += rr.x; v.y += rr.y; v.z += rr.z; v.w += rr.w;
            *(float4*)((float*)Cout + (size_t)tok * N + chan) = v;
        }
    }
}

// ---------------------------------------------------------------- deformable sampling
// vbuf layout [b*NVTOT+pix][h*d]: wave-uniform base + 32-bit byte offsets (meta
// stores pix<<9); lane = (h, c8), per-lane byte bias = lane*8.
__global__ __launch_bounds__(256)
void sample_k(const __hip_bfloat16* __restrict__ v, const __hip_bfloat16* __restrict__ cbuf,
              const float* __restrict__ ref, __hip_bfloat16* __restrict__ out)
{
    __shared__ int4   metaIdx[4 * 104];   // stride 13 slots -> conflict-free
    __shared__ float4 metaW[4 * 104];

    int wid  = threadIdx.x >> 6;
    int lane = threadIdx.x & 63;
    int t    = blockIdx.x * 4 + wid;
    int b    = t >> 14;
    float rx = ref[(size_t)t * 2 + 0];
    float ry = ref[(size_t)t * 2 + 1];
    const __hip_bfloat16* crow = cbuf + (size_t)t * NPROJ;

    #pragma unroll
    for (int rnd = 0; rnd < 2; rnd++) {
        int slot = rnd * 64 + lane;
        int h = slot >> 4, p = slot & 15;
        int pc = imin(p, 11);
        unsigned upk = *(const unsigned*)(crow + h * 24 + pc * 2);
        float ox = bf2f((unsigned short)upk);
        float oy = bf2f((unsigned short)(upk >> 16));
        float logit = bf2f(*(const unsigned short*)(crow + 192 + h * 12 + pc));
        float mx = logit;
        #pragma unroll
        for (int o = 8; o > 0; o >>= 1) mx = fmaxf(mx, __shfl_xor(mx, o, 16));
        float e = (p < 12) ? __expf(logit - mx) : 0.0f;
        float ssum = e;
        #pragma unroll
        for (int o = 8; o > 0; o >>= 1) ssum += __shfl_xor(ssum, o, 16);
        float aw = e * __builtin_amdgcn_rcpf(ssum);

        if (p < 12) {
            int l = p >> 2;
            float fS = (l == 0) ? 100.0f : ((l == 1) ? 50.0f : 25.0f);
            int   Wl = (l == 0) ? 100 : ((l == 1) ? 50 : 25);
            int   st = (l == 0) ? 0 : ((l == 1) ? 10000 : 12500);
            float x = fmaf(rx, fS, ox) - 0.5f;   // == (rx + ox/fS)*fS - 0.5
            float y = fmaf(ry, fS, oy) - 0.5f;
            float x0f = floorf(x), y0f = floorf(y);
            float fx = x - x0f, fy = y - y0f;
            int x0 = (int)x0f, y0 = (int)y0f;
            int x1 = x0 + 1,  y1 = y0 + 1;
            int cx0 = imin(imax(x0, 0), Wl - 1), cx1 = imin(imax(x1, 0), Wl - 1);
            int cy0 = imin(imax(y0, 0), Wl - 1), cy1 = imin(imax(y1, 0), Wl - 1);
            float vx0 = (x0 >= 0 && x0 < Wl) ? 1.0f : 0.0f;
            float vx1 = (x1 >= 0 && x1 < Wl) ? 1.0f : 0.0f;
            float vy0 = (y0 >= 0 && y0 < Wl) ? 1.0f : 0.0f;
            float vy1 = (y1 >= 0 && y1 < Wl) ? 1.0f : 0.0f;
            int s = wid * 104 + h * 13 + p;
            metaIdx[s] = make_int4((st + cy0 * Wl + cx0) << 9, (st + cy0 * Wl + cx1) << 9,
                                   (st + cy1 * Wl + cx0) << 9, (st + cy1 * Wl + cx1) << 9);
            metaW[s] = make_float4((1.0f - fx) * (1.0f - fy) * aw * vx0 * vy0,
                                   fx * (1.0f - fy) * aw * vx1 * vy0,
                                   (1.0f - fx) * fy * aw * vx0 * vy1,
                                   fx * fy * aw * vx1 * vy1);
        }
    }
    __syncthreads();

    int h  = lane >> 3;
    int bs = __builtin_amdgcn_readfirstlane(b);
    const char* vb = (const char*)(v + (size_t)bs * NVTOT * CDIM);
    int hoff = lane * 8;    // (h*32 + c8*4) * 2 bytes
    float4 acc = {0.0f, 0.0f, 0.0f, 0.0f};
    #pragma unroll
    for (int p = 0; p < 12; p++) {
        int s = wid * 104 + h * 13 + p;
        int4   mi = metaIdx[s];
        float4 mw = metaW[s];
        u64 g0 = *(const u64*)(vb + (unsigned)(mi.x + hoff));
        u64 g1 = *(const u64*)(vb + (unsigned)(mi.y + hoff));
        u64 g2 = *(const u64*)(vb + (unsigned)(mi.z + hoff));
        u64 g3 = *(const u64*)(vb + (unsigned)(mi.w + hoff));
        {
            unsigned d0 = (unsigned)g0, d1 = (unsigned)(g0 >> 32);
            acc.x = fmaf(mw.x, __uint_as_float(d0 << 16), acc.x);
            acc.y = fmaf(mw.x, __uint_as_float(d0 & 0xffff0000u), acc.y);
            acc.z = fmaf(mw.x, __uint_as_float(d1 << 16), acc.z);
            acc.w = fmaf(mw.x, __uint_as_float(d1 & 0xffff0000u), acc.w);
        }
        {
            unsigned d0 = (unsigned)g1, d1 = (unsigned)(g1 >> 32);
            acc.x = fmaf(mw.y, __uint_as_float(d0 << 16), acc.x);
            acc.y = fmaf(mw.y, __uint_as_float(d0 & 0xffff0000u), acc.y);
            acc.z = fmaf(mw.y, __uint_as_float(d1 << 16), acc.z);
            acc.w = fmaf(mw.y, __uint_as_float(d1 & 0xffff0000u), acc.w);
        }
        {
            unsigned d0 = (unsigned)g2, d1 = (unsigned)(g2 >> 32);
            acc.x = fmaf(mw.z, __uint_as_float(d0 << 16), acc.x);
            acc.y = fmaf(mw.z, __uint_as_float(d0 & 0xffff0000u), acc.y);
            acc.z = fmaf(mw.z, __uint_as_float(d1 << 16), acc.z);
            acc.w = fmaf(mw.z, __uint_as_float(d1 & 0xffff0000u), acc.w);
        }
        {
            unsigned d0 = (unsigned)g3, d1 = (unsigned)(g3 >> 32);
            acc.x = fmaf(mw.w, __uint_as_float(d0 << 16), acc.x);
            acc.y = fmaf(mw.w, __uint_as_float(d0 & 0xffff0000u), acc.y);
            acc.z = fmaf(mw.w, __uint_as_float(d1 << 16), acc.z);
            acc.w = fmaf(mw.w, __uint_as_float(d1 & 0xffff0000u), acc.w);
        }
    }
    *(u64*)(out + (size_t)t * CDIM + lane * 4) = pack4(acc);
}

// ---------------------------------------------------------------- launch
extern "C" void kernel_launch(void* const* d_in, const int* in_sizes, int n_in,
                              void* d_out, int out_size, void* d_ws, size_t ws_size,
                              hipStream_t stream)
{
    const float* query = (const float*)d_in[0];
    const float* value = (const float*)d_in[1];
    const float* qpos  = (const float*)d_in[2];
    const float* ref   = (const float*)d_in[3];
    const float* ln1g  = (const float*)d_in[6];
    const float* ln1b  = (const float*)d_in[7];
    const float* ln2g  = (const float*)d_in[8];
    const float* ln2b  = (const float*)d_in[9];
    const float* Wv    = (const float*)d_in[10];
    const float* bv    = (const float*)d_in[11];
    const float* Woff  = (const float*)d_in[12];
    const float* boff  = (const float*)d_in[13];
    const float* Wat   = (const float*)d_in[14];
    const float* bat   = (const float*)d_in[15];
    const float* Wout  = (const float*)d_in[16];
    const float* bout  = (const float*)d_in[17];
    const float* W1    = (const float*)d_in[18];
    const float* b1    = (const float*)d_in[19];
    const float* W2    = (const float*)d_in[20];
    const float* b2    = (const float*)d_in[21];
    float* out = (float*)d_out;
    char*  ws  = (char*)d_ws;

    const size_t MB = 1024 * 1024;
    __hip_bfloat16* Wvt   = (__hip_bfloat16*)(ws + 0);        // 256*256
    __hip_bfloat16* Wct   = (__hip_bfloat16*)(ws + 131072);   // 384*256 combined proj
    __hip_bfloat16* Woutt = (__hip_bfloat16*)(ws + 327680);   // 256*256
    __hip_bfloat16* W1t   = (__hip_bfloat16*)(ws + 458752);   // 1024*256
    __hip_bfloat16* W2t   = (__hip_bfloat16*)(ws + 983040);   // 256*1024
    float*          bcomb = (float*)(ws + 1507328);           // 288 floats
    __hip_bfloat16* qbf   = (__hip_bfloat16*)(ws + 2  * MB);  // 16.78 MB; reused as h
    __hip_bfloat16* aoutb = (__hip_bfloat16*)(ws + 19 * MB);  // 16.78 MB
    __hip_bfloat16* vbf   = (__hip_bfloat16*)(ws + 36 * MB);  // 13.44 MB bf16 value input
    __hip_bfloat16* vbuf  = (__hip_bfloat16*)(ws + 50 * MB);  // 13.44 MB projected v [row][h*d]
    __hip_bfloat16* xbf   = (__hip_bfloat16*)(ws + 64 * MB);  // 16.78 MB x (bf16)
    __hip_bfloat16* cbuf  = (__hip_bfloat16*)(ws + 81 * MB);  // 18.87 MB fused proj
    __hip_bfloat16* gbf   = (__hip_bfloat16*)(ws + 100 * MB); // 67.1 MB gelu acts
    __hip_bfloat16* hbf   = qbf;

    // 1. prep: weights->bf16 transposed, value->bf16, LN1(+pos)->qbf
    prep_k<<<WT_BLOCKS + CVT_BLOCKS + LN_BLOCKS, 256, 0, stream>>>(
        Wv, Woff, Wat, Wout, W1, W2, boff, bat, value, query, qpos, ln1g, ln1b,
        Wvt, Wct, Woutt, W1t, W2t, bcomb, vbf, qbf);
    // 2. v-proj: vbuf[row][h*d] = value @ W_value + b_value  (plain coalesced bf16)
    mm_k<<<dim3((MROWS_V + 127) / 128, 2), 256, 0, stream>>>(
        vbf, Wvt, bv, nullptr, vbuf, MROWS_V, 256, 256, EP_PLAIN_BF16);
    // 3. fused proj: [offsets | attn logits] (bf16)
    mm_k<<<dim3(NTOK / 128, 3), 256, 0, stream>>>(
        qbf, Wct, bcomb, nullptr, cbuf, NTOK, NPROJ, 256, EP_PLAIN_BF16);
    // 4. sampling (inline softmax) -> aout bf16
    sample_k<<<NTOK / 4, 256, 0, stream>>>(vbuf, cbuf, ref, aoutb);
    // 5. x = query + aout @ W_out + b_out -> xbf (bf16)
    mm_k<<<dim3(NTOK / 128, 2), 256, 0, stream>>>(
        aoutb, Woutt, bout, query, xbf, NTOK, 256, 256, EP_RES_F2BF);
    // 6. h = LN2(x) bf16
    ln2_k<<<NTOK / 4, 256, 0, stream>>>(xbf, ln2g, ln2b, hbf);
    // 7. g = gelu(h @ W_ffn1 + b_ffn1) bf16
    mm_k<<<dim3(NTOK / 128, 8), 256, 0, stream>>>(
        hbf, W1t, b1, nullptr, gbf, NTOK, FDIM, 256, EP_GELU_BF16);
    // 8. out = x + g @ W_ffn2 + b_ffn2  (fp32 to d_out)
    mm_k<<<dim3(NTOK / 128, 2), 256, 0, stream>>>(
        gbf, W2t, b2, xbf, out, NTOK, 256, 1024, EP_RES_BF2F);
}